// Round 1
// baseline (540.831 us; speedup 1.0000x reference)
//
#include <hip/hip_runtime.h>
#include <math.h>

#define BS 128
#define GS 2000
#define E  128
#define KMAXI 4
#define CLIPV 10.0f
#define NEGV  -1.0e30f

typedef __bf16 bf16_t;
typedef __bf16 bf16x8 __attribute__((ext_vector_type(8)));
typedef __bf16 bf16x4 __attribute__((ext_vector_type(4)));
typedef float fx4 __attribute__((ext_vector_type(4)));
typedef float fx2 __attribute__((ext_vector_type(2)));

__device__ __forceinline__ float fast_sigmoid(float x){ return 1.0f/(1.0f+__expf(-x)); }
__device__ __forceinline__ float fast_tanhf(float x){
    float e = __expf(2.0f*x);
    return 1.0f - 2.0f/(e + 1.0f);
}
// Padé(3,2) tanh clamped at |x|=3 — used only in the tiny epilogue (8/thread).
__device__ __forceinline__ float pade_tanh(float x){
    float t = __builtin_amdgcn_fmed3f(x, -3.0f, 3.0f);
    float r = t*t;
    float num = t*(27.0f + r);
    float den = fmaf(9.0f, r, 27.0f);
    return num * __builtin_amdgcn_rcpf(den);
}
// Packed odd-poly tanh, clamp at |x|=3 (max err ~0.036; rcp-free, pk_fma-friendly).
// Coeffs from collocation at t = {0.5, 1.5, 2.5, 3.0}; continuous at clamp (t=3 -> 0.99511).
__device__ __forceinline__ fx2 tanh2_poly(fx2 x){
    fx2 t;
    t.x = __builtin_amdgcn_fmed3f(x.x, -3.0f, 3.0f);
    t.y = __builtin_amdgcn_fmed3f(x.y, -3.0f, 3.0f);
    fx2 r = t*t;
    fx2 q = r*(-0.0015650f) + 0.03172875f;
    q = q*r + (-0.23082094f);
    q = q*r + 0.979947f;
    return t*q;
}
__device__ __forceinline__ int pymod(int a){ int d = a % GS; return d < 0 ? d + GS : d; }

// scalars layout per b (stride 64 ints): [0]=a0 ; per it at 8+it*8:
// +0 action, +1 old_stopped, +2 new_stopped, +3 allow, +4 vta, +5 row1, +6 row2
#define SC_STRIDE 64

// ---------------------------------------------------------------- integer trajectory (1 block, t = b)
__global__ __launch_bounds__(128) void k_traj(
    const int* __restrict__ rec, const int* __restrict__ vtime,
    const int* __restrict__ last_action, const int* __restrict__ fixed_action,
    int* __restrict__ sc, float* __restrict__ out)
{
    int b = threadIdx.x;
    if (b >= BS) return;
    int stopped = 1, nol = -1;
    int ai[4]={0,0,0,0}, kl[5]={0,0,0,0,0}, kr[4]={0,0,0,0};
    int a0 = 0;
    int* scb = sc + b*SC_STRIDE;
    for (int it=0; it<KMAXI; ++it){
        int action = (it==0) ? fixed_action[b*KMAXI]
                             : (stopped ? ai[0] : fixed_action[b*KMAXI+it]);
        int old_stopped = stopped;
        if (it==0) a0 = action;
        int vta = (it==0) ? 0 : pymod(vtime[(size_t)b*GS+action] - vtime[(size_t)b*GS+a0]);
        int nna = rec[(size_t)b*GS+action];
        int eq  = (action == nol) ? 1 : 0;
        int new_stopped = (it==0) ? eq : (stopped | eq);
        int ai0 = (it==0) ? action : ai[0];
        int allow = (!new_stopped) && (nna == ai0);

        ai[it] = action;
        if (old_stopped)  kl[it] = action;
        if (!old_stopped) kr[(it+3)&3] = action;
        kl[it+1] = nna;
        if (new_stopped) kl[it] = kl[(it+4)%5];
        if (new_stopped) kr[it] = kr[(it+3)&3];

        int row1 = action;
        int i2 = pymod(nol);
        int row2 = old_stopped ? row1 : i2;

        int* s_it = scb + 8 + it*8;
        s_it[0]=action; s_it[1]=old_stopped; s_it[2]=new_stopped;
        s_it[3]=allow;  s_it[4]=vta; s_it[5]=row1; s_it[6]=row2;

        nol = new_stopped ? -1 : nna;
        stopped = new_stopped;
    }
    scb[0] = a0;
    if (!stopped) kr[3] = kl[4];
    out[BS*12 + b] = 0.0f;   // zero the ll slot; k_ll atomicAdds into it (runs later in-stream)
    for (int j=0;j<4;++j) out[b*12+j]   = (float)ai[j];
    for (int j=0;j<4;++j) out[b*12+4+j] = (float)kl[j];
    for (int j=0;j<4;++j) out[b*12+8+j] = (float)kr[j];
}

// ---------------------------------------------------------------- h mean partials
__global__ __launch_bounds__(256) void k_hmean(const float* __restrict__ h, float* __restrict__ hpart){
    int b = blockIdx.x, p = blockIdx.y, tid = threadIdx.x;
    int e4 = (tid & 31) * 4;
    int gsub = tid >> 5;
    float4 acc = {0.f,0.f,0.f,0.f};
    int g0 = p*125, g1 = g0+125;
    for (int g = g0 + gsub; g < g1; g += 8){
        float4 v = *(const float4*)(h + ((size_t)b*GS + g)*E + e4);
        acc.x += v.x; acc.y += v.y; acc.z += v.z; acc.w += v.w;
    }
    __shared__ float ps[8][E];
    *(float4*)(&ps[gsub][e4]) = acc;
    __syncthreads();
    if (tid < E){
        float s = 0.f;
        #pragma unroll
        for (int j=0;j<8;++j) s += ps[j][tid];
        hpart[(b*16+p)*E + tid] = s;
    }
}

__device__ __forceinline__ float dot32(const float* a, const float* __restrict__ w){
    const float4* a4=(const float4*)a; const float4* w4=(const float4*)w;
    float s=0.f;
    #pragma unroll 8
    for (int i=0;i<32;++i){ float4 x=a4[i], y=w4[i]; s += x.x*y.x + x.y*y.y + x.z*y.z + x.w*y.w; }
    return s;
}

// ---------------------------------------------------------------- all 4 GRU steps, batched (b, rnn) blocks
__global__ __launch_bounds__(128) void k_gru4(
    const float* __restrict__ hpart, const float* __restrict__ W_init,
    const float* __restrict__ b_init, const float* __restrict__ init_query,
    const float* __restrict__ h, const int* __restrict__ sc,
    const float* __restrict__ Wih1, const float* __restrict__ Whh1,
    const float* __restrict__ bih1, const float* __restrict__ bhh1,
    const float* __restrict__ Wih2, const float* __restrict__ Whh2,
    const float* __restrict__ bih2, const float* __restrict__ bhh2,
    const float* __restrict__ WQ1, const float* __restrict__ WQ2,
    const float* __restrict__ WQ3, const float* __restrict__ WQ4,
    float* __restrict__ add_buf, float* __restrict__ mul_buf)
{
    int b = blockIdx.x, rnn = blockIdx.y, t = threadIdx.x;
    const float* Wih = rnn ? Wih2 : Wih1;
    const float* Whh = rnn ? Whh2 : Whh1;
    const float* bih = rnn ? bih2 : bih1;
    const float* bhh = rnn ? bhh2 : bhh1;
    const float* WQa = rnn ? WQ2 : WQ1;
    const float* WQm = rnn ? WQ4 : WQ3;

    __shared__ float xv[E], hv[E];
    // hmean -> q0
    {
        float s = 0.f;
        for (int p=0;p<16;++p) s += hpart[(b*16+p)*E + t];
        xv[t] = s * (1.0f/(float)GS);
    }
    __syncthreads();
    float q0 = b_init[t] + dot32(xv, W_init + (size_t)t*E);
    __syncthreads();
    hv[t] = q0;
    xv[t] = init_query[t];
    __syncthreads();

    for (int s=0; s<KMAXI; ++s){
        if (s>0){
            int row = sc[b*SC_STRIDE + 8 + (s-1)*8 + (rnn==0 ? 5 : 6)];
            xv[t] = h[((size_t)b*GS + row)*E + t];
            __syncthreads();
        }
        float gr=bih[t], gz=bih[t+E], gn=bih[t+2*E];
        float hr=bhh[t], hz=bhh[t+E], hn=bhh[t+2*E];
        {
            const float4* x4 = (const float4*)xv;
            const float4* h4 = (const float4*)hv;
            const float4* wr=(const float4*)(Wih+(size_t)t*E);
            const float4* wz=(const float4*)(Wih+(size_t)(t+E)*E);
            const float4* wn=(const float4*)(Wih+(size_t)(t+2*E)*E);
            const float4* vr=(const float4*)(Whh+(size_t)t*E);
            const float4* vz=(const float4*)(Whh+(size_t)(t+E)*E);
            const float4* vn=(const float4*)(Whh+(size_t)(t+2*E)*E);
            #pragma unroll 4
            for (int i=0;i<32;++i){
                float4 x=x4[i], h0=h4[i];
                float4 a=wr[i];  gr += x.x*a.x + x.y*a.y + x.z*a.z + x.w*a.w;
                float4 bq=wz[i]; gz += x.x*bq.x + x.y*bq.y + x.z*bq.z + x.w*bq.w;
                float4 cq=wn[i]; gn += x.x*cq.x + x.y*cq.y + x.z*cq.z + x.w*cq.w;
                float4 d=vr[i];  hr += h0.x*d.x + h0.y*d.y + h0.z*d.z + h0.w*d.w;
                float4 e=vz[i];  hz += h0.x*e.x + h0.y*e.y + h0.z*e.z + h0.w*e.w;
                float4 f=vn[i];  hn += h0.x*f.x + h0.y*f.y + h0.z*f.z + h0.w*f.w;
            }
        }
        float r = fast_sigmoid(gr+hr);
        float z = fast_sigmoid(gz+hz);
        float n = fast_tanhf(gn + r*hn);
        float hnew = (1.f-z)*n + z*hv[t];
        __syncthreads();            // all dots done reading hv
        hv[t] = hnew;
        __syncthreads();
        float a = dot32(hv, WQa + (size_t)t*E);
        float m = dot32(hv, WQm + (size_t)t*E);
        int slot = s*2 + rnn;
        add_buf[(size_t)slot*BS*E + b*E + t] = a;
        mul_buf[(size_t)slot*BS*E + b*E + t] = m;
        __syncthreads();            // projections done reading hv before next xv/hv update
    }
}

// ---------------------------------------------------------------- M build, all 8 (it,arm) slots
__global__ __launch_bounds__(256) void k_mbuild(
    const float* __restrict__ WK1, const float* __restrict__ WK2,
    const float* __restrict__ WK3, const float* __restrict__ WK4,
    const float* __restrict__ mul_buf, bf16_t* __restrict__ Mb)
{
    int b = blockIdx.x, slot = blockIdx.y, tid = threadIdx.x;
    int arm = slot & 1;
    const float* WKa = arm ? WK2 : WK1;
    const float* WKm = arm ? WK4 : WK3;
    const float* mul = mul_buf + (size_t)slot*BS*E + b*E;
    __shared__ float mv[E];
    if (tid < E) mv[tid] = mul[tid];
    __syncthreads();
    bf16_t* outp = Mb + ((size_t)slot*BS + b)*E*E;
    #pragma unroll 4
    for (int j=0;j<16;++j){
        int u = j*256 + tid;          // 0..4095
        int f = u >> 5, e4 = (u & 31) * 4;
        float mf = mv[f];
        float4 a = *(const float4*)(WKa + (size_t)f*E + e4);
        float4 m = *(const float4*)(WKm + (size_t)f*E + e4);
        bf16x4 o;
        o[0]=(bf16_t)(a.x + m.x*mf);
        o[1]=(bf16_t)(a.y + m.y*mf);
        o[2]=(bf16_t)(a.z + m.z*mf);
        o[3]=(bf16_t)(a.w + m.w*mf);
        *(bf16x4*)(outp + (size_t)f*E + e4) = o;
    }
}

// ---------------------------------------------------------------- scores: all 4 iterations, A-frags loaded once
// launch_bounds (256,4): LDS 34816*4 = 139 KB <= 160 KB, VGPR cap 128 (was 116 at (256,2))
__global__ __launch_bounds__(256,4) void k_scores(
    const float* __restrict__ hf, const bf16_t* __restrict__ Mb,
    const float* __restrict__ add_buf,
    const float* __restrict__ V1, const float* __restrict__ V2,
    float* __restrict__ raw4)
{
    constexpr int LDW = 136;
    __shared__ bf16_t sM[E*LDW];     // 34816 B
    int b = blockIdx.x, yc = blockIdx.y, tid = threadIdx.x;
    int wave = tid >> 6, lane = tid & 63;
    int qd = lane >> 4, cl = lane & 15;
    int gbase = yc*128 + wave*32;

    // A fragments: 2 sets x 16 g-rows, K=128 (32 VGPRs)
    bf16x8 afr[2][4];
    #pragma unroll
    for (int set=0; set<2; ++set){
        int grow = gbase + set*16 + cl;
        if (grow >= GS) grow = GS-1;
        const float* hrow = hf + ((size_t)b*GS + grow)*E;
        #pragma unroll
        for (int s=0;s<4;++s){
            const float* p = hrow + s*32 + qd*8;
            float4 u0 = *(const float4*)(p);
            float4 u1 = *(const float4*)(p+4);
            bf16x8 a;
            a[0]=(bf16_t)u0.x; a[1]=(bf16_t)u0.y; a[2]=(bf16_t)u0.z; a[3]=(bf16_t)u0.w;
            a[4]=(bf16_t)u1.x; a[5]=(bf16_t)u1.y; a[6]=(bf16_t)u1.z; a[7]=(bf16_t)u1.w;
            afr[set][s]=a;
        }
    }

    for (int it=0; it<KMAXI; ++it){
        // packed accumulators: [set][row-pair]
        fx2 s00={0.f,0.f}, s01={0.f,0.f}, s10={0.f,0.f}, s11={0.f,0.f};
        #pragma unroll
        for (int arm=0; arm<2; ++arm){
            int slot = it*2 + arm;
            const bf16x8* Gm = (const bf16x8*)(Mb + ((size_t)slot*BS + b)*E*E);
            const float* addv = add_buf + (size_t)slot*BS*E + b*E;
            const float* Vv = arm ? V2 : V1;

            __syncthreads();
            #pragma unroll
            for (int k=0;k<8;++k){
                int u = k*256 + tid;
                bf16x8 v = Gm[u];
                *(bf16x8*)(sM + (u>>4)*LDW + (u&15)*8) = v;
            }
            __syncthreads();

            #pragma unroll
            for (int tf=0; tf<8; ++tf){
                int f = tf*16 + cl;
                float av = addv[f], vv = Vv[f];
                bf16x8 b1[4];
                #pragma unroll
                for (int s=0;s<4;++s)
                    b1[s] = *(const bf16x8*)(sM + f*LDW + s*32 + qd*8);
                // fold add[f] into the accumulator init (C layout: col=f for all 4 regs)
                fx4 a0 = {av,av,av,av};
                fx4 a1 = {av,av,av,av};
                #pragma unroll
                for (int s=0;s<4;++s){
                    a0 = __builtin_amdgcn_mfma_f32_16x16x32_bf16(afr[0][s], b1[s], a0, 0,0,0);
                    a1 = __builtin_amdgcn_mfma_f32_16x16x32_bf16(afr[1][s], b1[s], a1, 0,0,0);
                }
                fx2 vv2 = {vv, vv};
                s00 += vv2 * tanh2_poly((fx2){a0[0], a0[1]});
                s01 += vv2 * tanh2_poly((fx2){a0[2], a0[3]});
                s10 += vv2 * tanh2_poly((fx2){a1[0], a1[1]});
                s11 += vv2 * tanh2_poly((fx2){a1[2], a1[3]});
            }
        }
        #pragma unroll
        for (int set=0;set<2;++set){
            fx2 pa = set ? s10 : s00;
            fx2 pb = set ? s11 : s01;
            float v[4] = {pa.x, pa.y, pb.x, pb.y};
            #pragma unroll
            for (int r=0;r<4;++r){
                float s = v[r];
                s += __shfl_xor(s, 1); s += __shfl_xor(s, 2);
                s += __shfl_xor(s, 4); s += __shfl_xor(s, 8);
                v[r] = s;
            }
            if (cl==0){
                int gi = gbase + set*16 + qd*4;
                if (gi+3 < GS){
                    float4 o;
                    o.x = CLIPV*pade_tanh(v[0]);
                    o.y = CLIPV*pade_tanh(v[1]);
                    o.z = CLIPV*pade_tanh(v[2]);
                    o.w = CLIPV*pade_tanh(v[3]);
                    *(float4*)(raw4 + ((size_t)it*BS + b)*GS + gi) = o;
                }
            }
        }
    }
}

// ---------------------------------------------------------------- ll: masked logsumexp, one (b,it) per block
__global__ __launch_bounds__(256) void k_ll(
    const float* __restrict__ raw4, const int* __restrict__ sc,
    const int* __restrict__ vtime, const int* __restrict__ last_action,
    float* __restrict__ out)
{
    __shared__ float sL[GS];
    __shared__ float red[256];
    int b = blockIdx.x, it = blockIdx.y, t = threadIdx.x;
    const int* scb = sc + b*SC_STRIDE;
    const int* s_it = scb + 8 + it*8;
    int action = s_it[0], olds = s_it[1];
    if (it>0 && olds) return;          // contribution is exactly 0 — uniform per block
    int a0 = scb[0];
    int la = last_action[b];
    int vt0 = vtime[(size_t)b*GS + a0];
    int ap=0, nsp=0, alp=0, vtp=0, p = it-1;
    if (it>0){
        const int* s_p = scb + 8 + p*8;
        ap = s_p[0]; nsp = s_p[2]; alp = s_p[3]; vtp = s_p[4];
    }
    for (int g=t; g<GS; g+=256){
        float l = raw4[((size_t)it*BS + b)*GS + g];
        int m;
        if (it==0){
            m = (g==la);
        } else {
            int d = pymod(vtime[(size_t)b*GS+g] - vt0);
            m = (d <= vtp) ? 1 : 0;
            if (p==0 && d > GS-2) m = 1;
            if (nsp && g==ap)     m = 0;
            if (alp && g==a0)     m = 0;
        }
        sL[g] = m ? NEGV : l;
    }
    __syncthreads();
    float mx = -3.0e38f;
    for (int g=t; g<GS; g+=256) mx = fmaxf(mx, sL[g]);
    red[t]=mx; __syncthreads();
    for (int s=128;s>0;s>>=1){ if(t<s) red[t]=fmaxf(red[t],red[t+s]); __syncthreads(); }
    mx = red[0]; __syncthreads();
    float sm = 0.f;
    for (int g=t; g<GS; g+=256) sm += __expf(sL[g]-mx);
    red[t]=sm; __syncthreads();
    for (int s=128;s>0;s>>=1){ if(t<s) red[t]+=red[t+s]; __syncthreads(); }
    if (t==0){
        float lse = mx + __logf(red[0]);
        atomicAdd(&out[BS*12 + b], sL[action] - lse);
    }
}

// ----------------------------------------------------------------
extern "C" void kernel_launch(void* const* d_in, const int* in_sizes, int n_in,
                              void* d_out, int out_size, void* d_ws, size_t ws_size,
                              hipStream_t stream)
{
    const float* h            = (const float*)d_in[0];
    const int*   rec          = (const int*)  d_in[1];
    /* d_in[2] = context2, unused by reference */
    const int*   vtime        = (const int*)  d_in[3];
    const int*   last_action  = (const int*)  d_in[4];
    const int*   fixed_action = (const int*)  d_in[5];
    const float* WK1=(const float*)d_in[6],  *WK2=(const float*)d_in[7];
    const float* WK3=(const float*)d_in[8],  *WK4=(const float*)d_in[9];
    const float* WQ1=(const float*)d_in[10], *WQ2=(const float*)d_in[11];
    const float* WQ3=(const float*)d_in[12], *WQ4=(const float*)d_in[13];
    const float* W_init=(const float*)d_in[14];
    const float* b_init=(const float*)d_in[15];
    const float* V1=(const float*)d_in[16], *V2=(const float*)d_in[17];
    const float* init_query=(const float*)d_in[18];
    const float* Wih1=(const float*)d_in[19], *Whh1=(const float*)d_in[20];
    const float* bih1=(const float*)d_in[21], *bhh1=(const float*)d_in[22];
    const float* Wih2=(const float*)d_in[23], *Whh2=(const float*)d_in[24];
    const float* bih2=(const float*)d_in[25], *bhh2=(const float*)d_in[26];
    float* out = (float*)d_out;

    char* ws = (char*)d_ws;
    size_t off = 0;
    auto alloc = [&](size_t bytes)->char*{
        char* p = ws + off; off += (bytes + 255) & ~(size_t)255; return p;
    };
    bf16_t* Mb     = (bf16_t*)alloc((size_t)8*BS*E*E*sizeof(bf16_t));   // 33.5 MB
    float*  raw4   = (float*) alloc((size_t)KMAXI*BS*GS*sizeof(float)); // 4.1 MB
    float*  add_buf= (float*) alloc((size_t)8*BS*E*sizeof(float));
    float*  mul_buf= (float*) alloc((size_t)8*BS*E*sizeof(float));
    float*  hpart  = (float*) alloc((size_t)BS*16*E*sizeof(float));
    int*    sc     = (int*)   alloc((size_t)BS*SC_STRIDE*sizeof(int));
    (void)in_sizes; (void)n_in; (void)out_size; (void)ws_size;

    hipLaunchKernelGGL(k_traj, dim3(1), dim3(128), 0, stream,
                       rec, vtime, last_action, fixed_action, sc, out);
    hipLaunchKernelGGL(k_hmean, dim3(BS,16), dim3(256), 0, stream, h, hpart);
    hipLaunchKernelGGL(k_gru4, dim3(BS,2), dim3(128), 0, stream,
                       hpart, W_init, b_init, init_query, h, sc,
                       Wih1,Whh1,bih1,bhh1, Wih2,Whh2,bih2,bhh2,
                       WQ1,WQ2,WQ3,WQ4, add_buf, mul_buf);
    hipLaunchKernelGGL(k_mbuild, dim3(BS,8), dim3(256), 0, stream,
                       WK1,WK2,WK3,WK4, mul_buf, Mb);
    hipLaunchKernelGGL(k_scores, dim3(BS,16), dim3(256), 0, stream,
                       h, Mb, add_buf, V1, V2, raw4);
    hipLaunchKernelGGL(k_ll, dim3(BS, KMAXI), dim3(256), 0, stream,
                       raw4, sc, vtime, last_action, out);
}

// Round 2
// 435.830 us; speedup vs baseline: 1.2409x; 1.2409x over previous
//
#include <hip/hip_runtime.h>
#include <math.h>

#define BS 128
#define GS 2000
#define E  128
#define KMAXI 4
#define CLIPV 10.0f
#define NEGV  -1.0e30f

typedef __bf16 bf16_t;
typedef __bf16 bf16x8 __attribute__((ext_vector_type(8)));
typedef float fx4 __attribute__((ext_vector_type(4)));
typedef float fx2 __attribute__((ext_vector_type(2)));

__device__ __forceinline__ float fast_sigmoid(float x){ return 1.0f/(1.0f+__expf(-x)); }
__device__ __forceinline__ float fast_tanhf(float x){
    float e = __expf(2.0f*x);
    return 1.0f - 2.0f/(e + 1.0f);
}
// Padé(3,2) tanh clamped at |x|=3 — used only in the tiny epilogue (8/thread).
__device__ __forceinline__ float pade_tanh(float x){
    float t = __builtin_amdgcn_fmed3f(x, -3.0f, 3.0f);
    float r = t*t;
    float num = t*(27.0f + r);
    float den = fmaf(9.0f, r, 27.0f);
    return num * __builtin_amdgcn_rcpf(den);
}
// Packed odd-poly tanh, clamp at |x|=3 (max err ~0.036; rcp-free, pk_fma-friendly).
__device__ __forceinline__ fx2 tanh2_poly(fx2 x){
    fx2 t;
    t.x = __builtin_amdgcn_fmed3f(x.x, -3.0f, 3.0f);
    t.y = __builtin_amdgcn_fmed3f(x.y, -3.0f, 3.0f);
    fx2 r = t*t;
    fx2 q = r*(-0.0015650f) + 0.03172875f;
    q = q*r + (-0.23082094f);
    q = q*r + 0.979947f;
    return t*q;
}
__device__ __forceinline__ int pymod(int a){ int d = a % GS; return d < 0 ? d + GS : d; }

// global -> LDS direct DMA, 16B per lane. lds per-lane ptr must be base + lane*16 (m97/m104).
__device__ __forceinline__ void load_lds16(const bf16_t* g, bf16_t* l){
    __builtin_amdgcn_global_load_lds(
        (const __attribute__((address_space(1))) void*)g,
        (__attribute__((address_space(3))) void*)l, 16, 0, 0);
}

// scalars layout per b (stride 64 ints): [0]=a0 ; per it at 8+it*8:
// +0 action, +1 old_stopped, +2 new_stopped, +3 allow, +4 vta, +5 row1, +6 row2
#define SC_STRIDE 64

// ---------------------------------------------------------------- integer trajectory (1 block, t = b)
__global__ __launch_bounds__(128) void k_traj(
    const int* __restrict__ rec, const int* __restrict__ vtime,
    const int* __restrict__ last_action, const int* __restrict__ fixed_action,
    int* __restrict__ sc, float* __restrict__ out)
{
    int b = threadIdx.x;
    if (b >= BS) return;
    int stopped = 1, nol = -1;
    int ai[4]={0,0,0,0}, kl[5]={0,0,0,0,0}, kr[4]={0,0,0,0};
    int a0 = 0;
    int* scb = sc + b*SC_STRIDE;
    for (int it=0; it<KMAXI; ++it){
        int action = (it==0) ? fixed_action[b*KMAXI]
                             : (stopped ? ai[0] : fixed_action[b*KMAXI+it]);
        int old_stopped = stopped;
        if (it==0) a0 = action;
        int vta = (it==0) ? 0 : pymod(vtime[(size_t)b*GS+action] - vtime[(size_t)b*GS+a0]);
        int nna = rec[(size_t)b*GS+action];
        int eq  = (action == nol) ? 1 : 0;
        int new_stopped = (it==0) ? eq : (stopped | eq);
        int ai0 = (it==0) ? action : ai[0];
        int allow = (!new_stopped) && (nna == ai0);

        ai[it] = action;
        if (old_stopped)  kl[it] = action;
        if (!old_stopped) kr[(it+3)&3] = action;
        kl[it+1] = nna;
        if (new_stopped) kl[it] = kl[(it+4)%5];
        if (new_stopped) kr[it] = kr[(it+3)&3];

        int row1 = action;
        int i2 = pymod(nol);
        int row2 = old_stopped ? row1 : i2;

        int* s_it = scb + 8 + it*8;
        s_it[0]=action; s_it[1]=old_stopped; s_it[2]=new_stopped;
        s_it[3]=allow;  s_it[4]=vta; s_it[5]=row1; s_it[6]=row2;

        nol = new_stopped ? -1 : nna;
        stopped = new_stopped;
    }
    scb[0] = a0;
    if (!stopped) kr[3] = kl[4];
    out[BS*12 + b] = 0.0f;   // zero the ll slot; k_ll atomicAdds into it (runs later in-stream)
    for (int j=0;j<4;++j) out[b*12+j]   = (float)ai[j];
    for (int j=0;j<4;++j) out[b*12+4+j] = (float)kl[j];
    for (int j=0;j<4;++j) out[b*12+8+j] = (float)kr[j];
}

// ---------------------------------------------------------------- h mean partials
__global__ __launch_bounds__(256) void k_hmean(const float* __restrict__ h, float* __restrict__ hpart){
    int b = blockIdx.x, p = blockIdx.y, tid = threadIdx.x;
    int e4 = (tid & 31) * 4;
    int gsub = tid >> 5;
    float4 acc = {0.f,0.f,0.f,0.f};
    int g0 = p*125, g1 = g0+125;
    for (int g = g0 + gsub; g < g1; g += 8){
        float4 v = *(const float4*)(h + ((size_t)b*GS + g)*E + e4);
        acc.x += v.x; acc.y += v.y; acc.z += v.z; acc.w += v.w;
    }
    __shared__ float ps[8][E];
    *(float4*)(&ps[gsub][e4]) = acc;
    __syncthreads();
    if (tid < E){
        float s = 0.f;
        #pragma unroll
        for (int j=0;j<8;++j) s += ps[j][tid];
        hpart[(b*16+p)*E + tid] = s;
    }
}

__device__ __forceinline__ float dot32(const float* a, const float* __restrict__ w){
    const float4* a4=(const float4*)a; const float4* w4=(const float4*)w;
    float s=0.f;
    #pragma unroll 8
    for (int i=0;i<32;++i){ float4 x=a4[i], y=w4[i]; s += x.x*y.x + x.y*y.y + x.z*y.z + x.w*y.w; }
    return s;
}

// ---------------------------------------------------------------- all 4 GRU steps, 384 threads:
// one (ih,hh) gate-row pair per thread, then 256 threads for the two projections.
__global__ __launch_bounds__(384) void k_gru4(
    const float* __restrict__ hpart, const float* __restrict__ W_init,
    const float* __restrict__ b_init, const float* __restrict__ init_query,
    const float* __restrict__ h, const int* __restrict__ sc,
    const float* __restrict__ Wih1, const float* __restrict__ Whh1,
    const float* __restrict__ bih1, const float* __restrict__ bhh1,
    const float* __restrict__ Wih2, const float* __restrict__ Whh2,
    const float* __restrict__ bih2, const float* __restrict__ bhh2,
    const float* __restrict__ WQ1, const float* __restrict__ WQ2,
    const float* __restrict__ WQ3, const float* __restrict__ WQ4,
    float* __restrict__ add_buf, float* __restrict__ mul_buf)
{
    int b = blockIdx.x, rnn = blockIdx.y, t = threadIdx.x;
    const float* Wih = rnn ? Wih2 : Wih1;
    const float* Whh = rnn ? Whh2 : Whh1;
    const float* bih = rnn ? bih2 : bih1;
    const float* bhh = rnn ? bhh2 : bhh1;
    const float* WQa = rnn ? WQ2 : WQ1;
    const float* WQm = rnn ? WQ4 : WQ3;

    __shared__ float xv[E], hv[E];
    __shared__ float gi_s[3*E], gh_s[3*E];

    if (t < E){
        float s = 0.f;
        for (int p=0;p<16;++p) s += hpart[(b*16+p)*E + t];
        xv[t] = s * (1.0f/(float)GS);
    }
    __syncthreads();
    if (t < E) hv[t] = b_init[t] + dot32(xv, W_init + (size_t)t*E);
    __syncthreads();
    if (t < E) xv[t] = init_query[t];
    __syncthreads();

    for (int s=0; s<KMAXI; ++s){
        if (s>0){
            if (t < E){
                int row = sc[b*SC_STRIDE + 8 + (s-1)*8 + (rnn==0 ? 5 : 6)];
                xv[t] = h[((size_t)b*GS + row)*E + t];
            }
            __syncthreads();
        }
        // 384 rows: gi[t], gh[t]
        {
            float gi = bih[t] + dot32(xv, Wih + (size_t)t*E);
            float gh = bhh[t] + dot32(hv, Whh + (size_t)t*E);
            gi_s[t] = gi; gh_s[t] = gh;
        }
        __syncthreads();
        if (t < E){
            float r = fast_sigmoid(gi_s[t]     + gh_s[t]);
            float z = fast_sigmoid(gi_s[t+E]   + gh_s[t+E]);
            float n = fast_tanhf  (gi_s[t+2*E] + r*gh_s[t+2*E]);
            hv[t] = (1.f-z)*n + z*hv[t];
        }
        __syncthreads();
        if (t < 2*E){
            int r = t & (E-1);
            const float* W = (t < E) ? WQa : WQm;
            float v = dot32(hv, W + (size_t)r*E);
            int slot = s*2 + rnn;
            if (t < E) add_buf[(size_t)slot*BS*E + b*E + r] = v;
            else       mul_buf[(size_t)slot*BS*E + b*E + r] = v;
        }
        __syncthreads();
    }
}

// ---------------------------------------------------------------- M build, all 8 (it,arm) slots
// Writes SWIZZLED chunk layout: 16B chunk (f,e8) stored at chunk index f*16 + (e8 ^ (f&7)).
// k_scores stages this image linearly via global_load_lds and reads with the same XOR.
__global__ __launch_bounds__(256) void k_mbuild(
    const float* __restrict__ WK1, const float* __restrict__ WK2,
    const float* __restrict__ WK3, const float* __restrict__ WK4,
    const float* __restrict__ mul_buf, bf16_t* __restrict__ Mb)
{
    int b = blockIdx.x, slot = blockIdx.y, tid = threadIdx.x;
    int arm = slot & 1;
    const float* WKa = arm ? WK2 : WK1;
    const float* WKm = arm ? WK4 : WK3;
    const float* mul = mul_buf + (size_t)slot*BS*E + b*E;
    __shared__ float mv[E];
    if (tid < E) mv[tid] = mul[tid];
    __syncthreads();
    bf16x8* outp = (bf16x8*)(Mb + ((size_t)slot*BS + b)*E*E);
    #pragma unroll
    for (int j=0;j<8;++j){
        int u = j*256 + tid;          // chunk id 0..2047
        int f = u >> 4, e8 = u & 15;
        int e0 = e8*8;
        float mf = mv[f];
        float4 a0 = *(const float4*)(WKa + (size_t)f*E + e0);
        float4 a1 = *(const float4*)(WKa + (size_t)f*E + e0 + 4);
        float4 m0 = *(const float4*)(WKm + (size_t)f*E + e0);
        float4 m1 = *(const float4*)(WKm + (size_t)f*E + e0 + 4);
        bf16x8 o;
        o[0]=(bf16_t)(a0.x + m0.x*mf);
        o[1]=(bf16_t)(a0.y + m0.y*mf);
        o[2]=(bf16_t)(a0.z + m0.z*mf);
        o[3]=(bf16_t)(a0.w + m0.w*mf);
        o[4]=(bf16_t)(a1.x + m1.x*mf);
        o[5]=(bf16_t)(a1.y + m1.y*mf);
        o[6]=(bf16_t)(a1.z + m1.z*mf);
        o[7]=(bf16_t)(a1.w + m1.w*mf);
        outp[f*16 + (e8 ^ (f&7))] = o;
    }
}

// ---------------------------------------------------------------- scores: all 4 iterations, A-frags loaded once
// (256,2): r1 showed forcing 4 blocks/CU caps VGPR at 64 -> 146MB spill traffic. Keep 2.
__global__ __launch_bounds__(256,2) void k_scores(
    const float* __restrict__ hf, const bf16_t* __restrict__ Mb,
    const float* __restrict__ add_buf,
    const float* __restrict__ V1, const float* __restrict__ V2,
    float* __restrict__ raw4)
{
    __shared__ bf16_t sM[E*E];       // 32768 B, linear DMA image (swizzled at source)
    int b = blockIdx.x, yc = blockIdx.y, tid = threadIdx.x;
    int wave = tid >> 6, lane = tid & 63;
    int qd = lane >> 4, cl = lane & 15;
    int gbase = yc*128 + wave*32;

    // V preload (per kernel): vv_r[arm][tf] = V[tf*16+cl]
    float vv_r[2][8];
    #pragma unroll
    for (int tf=0; tf<8; ++tf){
        vv_r[0][tf] = V1[tf*16+cl];
        vv_r[1][tf] = V2[tf*16+cl];
    }

    // A fragments: 2 sets x 16 g-rows, K=128 (32 VGPRs)
    bf16x8 afr[2][4];
    #pragma unroll
    for (int set=0; set<2; ++set){
        int grow = gbase + set*16 + cl;
        if (grow >= GS) grow = GS-1;
        const float* hrow = hf + ((size_t)b*GS + grow)*E;
        #pragma unroll
        for (int s=0;s<4;++s){
            const float* p = hrow + s*32 + qd*8;
            float4 u0 = *(const float4*)(p);
            float4 u1 = *(const float4*)(p+4);
            bf16x8 a;
            a[0]=(bf16_t)u0.x; a[1]=(bf16_t)u0.y; a[2]=(bf16_t)u0.z; a[3]=(bf16_t)u0.w;
            a[4]=(bf16_t)u1.x; a[5]=(bf16_t)u1.y; a[6]=(bf16_t)u1.z; a[7]=(bf16_t)u1.w;
            afr[set][s]=a;
        }
    }

    for (int it=0; it<KMAXI; ++it){
        // packed accumulators: [set][row-pair]
        fx2 s00={0.f,0.f}, s01={0.f,0.f}, s10={0.f,0.f}, s11={0.f,0.f};
        #pragma unroll
        for (int arm=0; arm<2; ++arm){
            int slot = it*2 + arm;
            const bf16_t* Gm = Mb + ((size_t)slot*BS + b)*E*E;
            const float* addv = add_buf + (size_t)slot*BS*E + b*E;

            // per-slot add preload (overlaps barrier+DMA latency)
            float av_r[8];
            #pragma unroll
            for (int tf=0; tf<8; ++tf) av_r[tf] = addv[tf*16+cl];

            __syncthreads();        // previous slot's sM reads complete
            // DMA stage: 8 x 1KB per wave, linear chunks (c = wave*512 + j*64 + lane)
            #pragma unroll
            for (int j=0;j<8;++j){
                int c = wave*512 + j*64 + lane;
                load_lds16(Gm + (size_t)c*8, sM + (size_t)c*8);
            }
            __syncthreads();        // vmcnt(0) drained by compiler before barrier

            #pragma unroll
            for (int tf=0; tf<8; ++tf){
                int f = tf*16 + cl;
                bf16x8 b1[4];
                #pragma unroll
                for (int s=0;s<4;++s){
                    int e8 = s*4 + qd;
                    b1[s] = *(const bf16x8*)(sM + ((size_t)(f*16 + (e8 ^ (f&7))))*8);
                }
                float av = av_r[tf];
                // fold add[f] into the accumulator init (C layout: col=f for all 4 regs)
                fx4 a0 = {av,av,av,av};
                fx4 a1 = {av,av,av,av};
                #pragma unroll
                for (int s=0;s<4;++s){
                    a0 = __builtin_amdgcn_mfma_f32_16x16x32_bf16(afr[0][s], b1[s], a0, 0,0,0);
                    a1 = __builtin_amdgcn_mfma_f32_16x16x32_bf16(afr[1][s], b1[s], a1, 0,0,0);
                }
                fx2 vv2 = {vv_r[arm][tf], vv_r[arm][tf]};
                s00 += vv2 * tanh2_poly((fx2){a0[0], a0[1]});
                s01 += vv2 * tanh2_poly((fx2){a0[2], a0[3]});
                s10 += vv2 * tanh2_poly((fx2){a1[0], a1[1]});
                s11 += vv2 * tanh2_poly((fx2){a1[2], a1[3]});
            }
        }
        #pragma unroll
        for (int set=0;set<2;++set){
            fx2 pa = set ? s10 : s00;
            fx2 pb = set ? s11 : s01;
            float v[4] = {pa.x, pa.y, pb.x, pb.y};
            #pragma unroll
            for (int r=0;r<4;++r){
                float s = v[r];
                s += __shfl_xor(s, 1); s += __shfl_xor(s, 2);
                s += __shfl_xor(s, 4); s += __shfl_xor(s, 8);
                v[r] = s;
            }
            if (cl==0){
                int gi = gbase + set*16 + qd*4;
                if (gi+3 < GS){
                    float4 o;
                    o.x = CLIPV*pade_tanh(v[0]);
                    o.y = CLIPV*pade_tanh(v[1]);
                    o.z = CLIPV*pade_tanh(v[2]);
                    o.w = CLIPV*pade_tanh(v[3]);
                    *(float4*)(raw4 + ((size_t)it*BS + b)*GS + gi) = o;
                }
            }
        }
    }
}

// ---------------------------------------------------------------- ll: masked logsumexp, one (b,it) per block
__global__ __launch_bounds__(256) void k_ll(
    const float* __restrict__ raw4, const int* __restrict__ sc,
    const int* __restrict__ vtime, const int* __restrict__ last_action,
    float* __restrict__ out)
{
    __shared__ float sL[GS];
    __shared__ float red[256];
    int b = blockIdx.x, it = blockIdx.y, t = threadIdx.x;
    const int* scb = sc + b*SC_STRIDE;
    const int* s_it = scb + 8 + it*8;
    int action = s_it[0], olds = s_it[1];
    if (it>0 && olds) return;          // contribution is exactly 0 — uniform per block
    int a0 = scb[0];
    int la = last_action[b];
    int vt0 = vtime[(size_t)b*GS + a0];
    int ap=0, nsp=0, alp=0, vtp=0, p = it-1;
    if (it>0){
        const int* s_p = scb + 8 + p*8;
        ap = s_p[0]; nsp = s_p[2]; alp = s_p[3]; vtp = s_p[4];
    }
    for (int g=t; g<GS; g+=256){
        float l = raw4[((size_t)it*BS + b)*GS + g];
        int m;
        if (it==0){
            m = (g==la);
        } else {
            int d = pymod(vtime[(size_t)b*GS+g] - vt0);
            m = (d <= vtp) ? 1 : 0;
            if (p==0 && d > GS-2) m = 1;
            if (nsp && g==ap)     m = 0;
            if (alp && g==a0)     m = 0;
        }
        sL[g] = m ? NEGV : l;
    }
    __syncthreads();
    float mx = -3.0e38f;
    for (int g=t; g<GS; g+=256) mx = fmaxf(mx, sL[g]);
    red[t]=mx; __syncthreads();
    for (int s=128;s>0;s>>=1){ if(t<s) red[t]=fmaxf(red[t],red[t+s]); __syncthreads(); }
    mx = red[0]; __syncthreads();
    float sm = 0.f;
    for (int g=t; g<GS; g+=256) sm += __expf(sL[g]-mx);
    red[t]=sm; __syncthreads();
    for (int s=128;s>0;s>>=1){ if(t<s) red[t]+=red[t+s]; __syncthreads(); }
    if (t==0){
        float lse = mx + __logf(red[0]);
        atomicAdd(&out[BS*12 + b], sL[action] - lse);
    }
}

// ----------------------------------------------------------------
extern "C" void kernel_launch(void* const* d_in, const int* in_sizes, int n_in,
                              void* d_out, int out_size, void* d_ws, size_t ws_size,
                              hipStream_t stream)
{
    const float* h            = (const float*)d_in[0];
    const int*   rec          = (const int*)  d_in[1];
    /* d_in[2] = context2, unused by reference */
    const int*   vtime        = (const int*)  d_in[3];
    const int*   last_action  = (const int*)  d_in[4];
    const int*   fixed_action = (const int*)  d_in[5];
    const float* WK1=(const float*)d_in[6],  *WK2=(const float*)d_in[7];
    const float* WK3=(const float*)d_in[8],  *WK4=(const float*)d_in[9];
    const float* WQ1=(const float*)d_in[10], *WQ2=(const float*)d_in[11];
    const float* WQ3=(const float*)d_in[12], *WQ4=(const float*)d_in[13];
    const float* W_init=(const float*)d_in[14];
    const float* b_init=(const float*)d_in[15];
    const float* V1=(const float*)d_in[16], *V2=(const float*)d_in[17];
    const float* init_query=(const float*)d_in[18];
    const float* Wih1=(const float*)d_in[19], *Whh1=(const float*)d_in[20];
    const float* bih1=(const float*)d_in[21], *bhh1=(const float*)d_in[22];
    const float* Wih2=(const float*)d_in[23], *Whh2=(const float*)d_in[24];
    const float* bih2=(const float*)d_in[25], *bhh2=(const float*)d_in[26];
    float* out = (float*)d_out;

    char* ws = (char*)d_ws;
    size_t off = 0;
    auto alloc = [&](size_t bytes)->char*{
        char* p = ws + off; off += (bytes + 255) & ~(size_t)255; return p;
    };
    bf16_t* Mb     = (bf16_t*)alloc((size_t)8*BS*E*E*sizeof(bf16_t));   // 33.5 MB
    float*  raw4   = (float*) alloc((size_t)KMAXI*BS*GS*sizeof(float)); // 4.1 MB
    float*  add_buf= (float*) alloc((size_t)8*BS*E*sizeof(float));
    float*  mul_buf= (float*) alloc((size_t)8*BS*E*sizeof(float));
    float*  hpart  = (float*) alloc((size_t)BS*16*E*sizeof(float));
    int*    sc     = (int*)   alloc((size_t)BS*SC_STRIDE*sizeof(int));
    (void)in_sizes; (void)n_in; (void)out_size; (void)ws_size;

    hipLaunchKernelGGL(k_traj, dim3(1), dim3(128), 0, stream,
                       rec, vtime, last_action, fixed_action, sc, out);
    hipLaunchKernelGGL(k_hmean, dim3(BS,16), dim3(256), 0, stream, h, hpart);
    hipLaunchKernelGGL(k_gru4, dim3(BS,2), dim3(384), 0, stream,
                       hpart, W_init, b_init, init_query, h, sc,
                       Wih1,Whh1,bih1,bhh1, Wih2,Whh2,bih2,bhh2,
                       WQ1,WQ2,WQ3,WQ4, add_buf, mul_buf);
    hipLaunchKernelGGL(k_mbuild, dim3(BS,8), dim3(256), 0, stream,
                       WK1,WK2,WK3,WK4, mul_buf, Mb);
    hipLaunchKernelGGL(k_scores, dim3(BS,16), dim3(256), 0, stream,
                       h, Mb, add_buf, V1, V2, raw4);
    hipLaunchKernelGGL(k_ll, dim3(BS, KMAXI), dim3(256), 0, stream,
                       raw4, sc, vtime, last_action, out);
}